// Round 1
// 2261.075 us; speedup vs baseline: 1.3060x; 1.3060x over previous
//
#include <hip/hip_runtime.h>
#include <hip/hip_bf16.h>
#include <stdint.h>

#define T_TOK 4096
#define DIN   4096
#define DOUT  4096
#define NE    8

typedef __attribute__((ext_vector_type(8))) short short8;
typedef __attribute__((ext_vector_type(4))) float floatx4;

__device__ inline uint32_t pk_bf16(float a, float b) {
    __hip_bfloat162 h = __float22bfloat162_rn(make_float2(a, b));
    union { __hip_bfloat162 h; uint32_t u; } cv;
    cv.h = h;
    return cv.u;
}

// async global->LDS, 16B per lane. HW writes at (wave-uniform lds base) + lane*16.
__device__ inline void gll16(const void* g, void* l) {
    __builtin_amdgcn_global_load_lds(
        (const __attribute__((address_space(1))) uint32_t*)g,
        (__attribute__((address_space(3))) uint32_t*)l, 16, 0, 0);
}

// ---------------- fp32 -> bf16 cast (8 elems/thread) ----------------
__global__ __launch_bounds__(256) void cast_bf16_kernel(const float* __restrict__ src,
                                                        uint16_t* __restrict__ dst) {
    size_t i = ((size_t)blockIdx.x * 256 + threadIdx.x) * 8;
    float4 a = *reinterpret_cast<const float4*>(src + i);
    float4 b = *reinterpret_cast<const float4*>(src + i + 4);
    uint4 p;
    p.x = pk_bf16(a.x, a.y); p.y = pk_bf16(a.z, a.w);
    p.z = pk_bf16(b.x, b.y); p.w = pk_bf16(b.z, b.w);
    *reinterpret_cast<uint4*>(dst + i) = p;
}

// ---------------- gate + routing (unchanged, verified) ----------------
__global__ __launch_bounds__(256) void gate_kernel(
    const float* __restrict__ x, const float* __restrict__ w1,
    const float* __restrict__ w2, int* __restrict__ perm,
    float* __restrict__ pscore, int* __restrict__ counts,
    float* __restrict__ importance)
{
    int t = blockIdx.x;
    int tid = threadIdx.x;
    int g = tid >> 5;      // expert group 0..7
    int l = tid & 31;
    const float* xr = x + (size_t)t * DIN;
    const float* wr = w1 + (size_t)g * DIN;
    float sum = 0.f;
    for (int i = l * 4; i < DIN; i += 128) {
        float4 xv = *reinterpret_cast<const float4*>(xr + i);
        float4 wv = *reinterpret_cast<const float4*>(wr + i);
        sum += xv.x * wv.x + xv.y * wv.y + xv.z * wv.z + xv.w * wv.w;
    }
#pragma unroll
    for (int off = 16; off; off >>= 1) sum += __shfl_xor(sum, off, 64);

    __shared__ float sh[NE];
    __shared__ float lg[NE];
    if (l == 0) sh[g] = tanhf(sum);
    __syncthreads();
    if (tid < NE) {
        float acc = 0.f;
#pragma unroll
        for (int e2 = 0; e2 < NE; ++e2) acc += sh[e2] * w2[tid * NE + e2];
        lg[tid] = acc;
    }
    __syncthreads();
    if (tid == 0) {
        int i1 = 0; float l1 = lg[0];
        for (int e2 = 1; e2 < NE; ++e2)
            if (lg[e2] > l1) { l1 = lg[e2]; i1 = e2; }
        int i2 = -1; float l2 = -1e30f;
        for (int e2 = 0; e2 < NE; ++e2)
            if (e2 != i1 && lg[e2] > l2) { l2 = lg[e2]; i2 = e2; }
        float ee = expf(l2 - l1);
        float p1 = 1.f / (1.f + ee);
        float p2 = ee / (1.f + ee);
        int pos1 = atomicAdd(&counts[i1], 1);
        perm[i1 * T_TOK + pos1] = t;
        pscore[i1 * T_TOK + pos1] = p1;
        int pos2 = atomicAdd(&counts[i2], 1);
        perm[i2 * T_TOK + pos2] = t;
        pscore[i2 * T_TOK + pos2] = p2;
        atomicAdd(&importance[i1], p1);
        atomicAdd(&importance[i2], p2);
    }
}

// ---------------- expert GEMM, m97 structure ----------------
// 128x128 tile, BK=32, 4 waves of 4x4 16x16x32 bf16 MFMA.
// A (gathered token rows) and B (bf16 weights when PRE) staged with
// global_load_lds width=16 into LINEAR 128x32 LDS tiles.
template<bool PRE>
__global__ __launch_bounds__(256) void moe_gemm_kernel(
    const uint16_t* __restrict__ xb, const uint16_t* __restrict__ wb,
    const float* __restrict__ ew, const float* __restrict__ eb,
    const int* __restrict__ perm, const float* __restrict__ pscore,
    const int* __restrict__ counts, float* __restrict__ out)
{
    const int e = blockIdx.z;
    const int ne = counts[e];
    const int m0 = blockIdx.x * 128;   // m fastest-varying: weight-strip sharers dispatch together
    if (m0 >= ne) return;
    const int n0 = blockIdx.y * 128;
    const int tid  = threadIdx.x;
    const int lane = tid & 63;
    const int wid  = tid >> 6;

    __shared__ int   s_tok[128];
    __shared__ float s_sc[128];
    __shared__ __align__(16) uint16_t As[128 * 32];  // linear: row*32 + k (64B rows)
    __shared__ __align__(16) uint16_t Bs[128 * 32];

    if (tid < 128) {
        int idx = m0 + tid;
        if (idx < ne) {
            s_tok[tid] = perm[e * T_TOK + idx];
            s_sc[tid]  = pscore[e * T_TOK + idx];
        } else {
            s_tok[tid] = -1;
            s_sc[tid]  = 0.f;
        }
    }
    __syncthreads();

    // staging geometry: issue covers 64 rows; lane -> (row, k-quad)
    const int srow = wid * 16 + (lane >> 2);   // 0..63
    const int sq   = (lane & 3) * 8;           // k element offset 0/8/16/24
    int t0 = s_tok[srow];      if (t0 < 0) t0 = 0;
    int t1 = s_tok[64 + srow]; if (t1 < 0) t1 = 0;
    const uint16_t* aS0 = xb + (size_t)t0 * DIN + sq;
    const uint16_t* aS1 = xb + (size_t)t1 * DIN + sq;
    uint16_t* aD0 = As + wid * 512;            // wave-uniform LDS bases
    uint16_t* aD1 = As + 2048 + wid * 512;
    uint16_t* bD0 = Bs + wid * 512;
    uint16_t* bD1 = Bs + 2048 + wid * 512;

    const uint16_t* bS0 = nullptr;
    const uint16_t* bS1 = nullptr;
    const float* fB = nullptr;
    uint16_t* fD = nullptr;
    if constexpr (PRE) {
        bS0 = wb + (size_t)e * DOUT * DIN + (size_t)(n0 + srow) * DIN + sq;
        bS1 = bS0 + (size_t)64 * DIN;
    } else {
        fB = ew + (size_t)e * DOUT * DIN + (size_t)(n0 + (tid >> 1)) * DIN + (tid & 1) * 16;
        fD = Bs + (tid >> 1) * 32 + (tid & 1) * 16;
    }

    const int wm   = (wid >> 1) * 64;
    const int wn   = (wid & 1) * 64;
    const int quad = lane >> 4;
    const int mr   = lane & 15;

    floatx4 acc[4][4] = {};

    for (int kk = 0; kk < DIN; kk += 32) {
        gll16(aS0 + kk, aD0);
        gll16(aS1 + kk, aD1);
        if constexpr (PRE) {
            gll16(bS0 + kk, bD0);
            gll16(bS1 + kk, bD1);
        } else {
            float4 f0 = *reinterpret_cast<const float4*>(fB + kk);
            float4 f1 = *reinterpret_cast<const float4*>(fB + kk + 4);
            float4 f2 = *reinterpret_cast<const float4*>(fB + kk + 8);
            float4 f3 = *reinterpret_cast<const float4*>(fB + kk + 12);
            uint4 b0, b1;
            b0.x = pk_bf16(f0.x, f0.y); b0.y = pk_bf16(f0.z, f0.w);
            b0.z = pk_bf16(f1.x, f1.y); b0.w = pk_bf16(f1.z, f1.w);
            b1.x = pk_bf16(f2.x, f2.y); b1.y = pk_bf16(f2.z, f2.w);
            b1.z = pk_bf16(f3.x, f3.y); b1.w = pk_bf16(f3.z, f3.w);
            *reinterpret_cast<uint4*>(fD)     = b0;
            *reinterpret_cast<uint4*>(fD + 8) = b1;
        }
        __syncthreads();

        short8 af[4], bf[4];
#pragma unroll
        for (int i = 0; i < 4; ++i)
            af[i] = *reinterpret_cast<const short8*>(&As[(wm + i * 16 + mr) * 32 + quad * 8]);
#pragma unroll
        for (int j = 0; j < 4; ++j)
            bf[j] = *reinterpret_cast<const short8*>(&Bs[(wn + j * 16 + mr) * 32 + quad * 8]);
#pragma unroll
        for (int i = 0; i < 4; ++i)
#pragma unroll
            for (int j = 0; j < 4; ++j)
                acc[i][j] = __builtin_amdgcn_mfma_f32_16x16x32_bf16(af[i], bf[j], acc[i][j], 0, 0, 0);
        __syncthreads();
    }

    // epilogue: out[tok, col] += score * (acc + bias)
    const float* brow = eb + (size_t)e * DOUT + n0 + wn;
    float bj[4];
#pragma unroll
    for (int j = 0; j < 4; ++j) bj[j] = brow[j * 16 + mr];
#pragma unroll
    for (int i = 0; i < 4; ++i) {
#pragma unroll
        for (int r = 0; r < 4; ++r) {
            int idx = wm + i * 16 + quad * 4 + r;
            int tok = s_tok[idx];
            if (tok < 0) continue;
            float sc = s_sc[idx];
            float* orow = out + (size_t)tok * DOUT + n0 + wn;
#pragma unroll
            for (int j = 0; j < 4; ++j)
                atomicAdd(&orow[j * 16 + mr], sc * (acc[i][j][r] + bj[j]));
        }
    }
}

// ---------------- balance loss ----------------
__global__ void balance_kernel(const int* __restrict__ counts,
                               const float* __restrict__ importance,
                               float* __restrict__ out_loss) {
    if (threadIdx.x == 0) {
        float mi = 0.f, ml = 0.f;
        for (int e = 0; e < NE; ++e) { mi += importance[e]; ml += (float)counts[e]; }
        mi /= NE; ml /= NE;
        float vi = 0.f, vl = 0.f;
        for (int e = 0; e < NE; ++e) {
            float di = importance[e] - mi; vi += di * di;
            float dl = (float)counts[e] - ml; vl += dl * dl;
        }
        vi /= (NE - 1); vl /= (NE - 1);
        *out_loss = 0.01f * (vi / (mi * mi + 1e-10f) + vl / (ml * ml + 1e-10f));
    }
}

extern "C" void kernel_launch(void* const* d_in, const int* in_sizes, int n_in,
                              void* d_out, int out_size, void* d_ws, size_t ws_size,
                              hipStream_t stream)
{
    const float* x  = (const float*)d_in[0];
    const float* w1 = (const float*)d_in[1];
    const float* w2 = (const float*)d_in[2];
    const float* ew = (const float*)d_in[3];
    const float* eb = (const float*)d_in[4];
    float* out = (float*)d_out;

    const size_t XB_BYTES = (size_t)T_TOK * DIN * 2;        // 32 MB  x in bf16
    const size_t WB_BYTES = (size_t)NE * DOUT * DIN * 2;    // 256 MB weights in bf16
    const size_t RT_BYTES = (size_t)8 * NE * T_TOK + 64;    // perm + pscore + counts + imp

    char* ws = (char*)d_ws;
    uint16_t* xb = (uint16_t*)ws;
    const bool pre = ws_size >= XB_BYTES + WB_BYTES + RT_BYTES;
    uint16_t* wb = (uint16_t*)(ws + XB_BYTES);
    char* rt = ws + XB_BYTES + (pre ? WB_BYTES : 0);
    int*   perm   = (int*)rt;
    float* pscore = (float*)(rt + (size_t)4 * NE * T_TOK);
    int*   counts = (int*)(rt + (size_t)8 * NE * T_TOK);
    float* imp    = (float*)(rt + (size_t)8 * NE * T_TOK + 32);

    hipMemsetAsync(counts, 0, 64, stream);
    hipMemsetAsync(d_out, 0, (size_t)out_size * sizeof(float), stream);

    cast_bf16_kernel<<<(int)(((size_t)T_TOK * DIN) / 2048), 256, 0, stream>>>(x, xb);
    gate_kernel<<<T_TOK, 256, 0, stream>>>(x, w1, w2, perm, pscore, counts, imp);
    if (pre) {
        cast_bf16_kernel<<<(int)(((size_t)NE * DOUT * DIN) / 2048), 256, 0, stream>>>(ew, wb);
        moe_gemm_kernel<true><<<dim3(32, 32, 8), 256, 0, stream>>>(
            xb, wb, ew, eb, perm, pscore, counts, out);
    } else {
        moe_gemm_kernel<false><<<dim3(32, 32, 8), 256, 0, stream>>>(
            xb, nullptr, ew, eb, perm, pscore, counts, out);
    }
    balance_kernel<<<1, 64, 0, stream>>>(counts, imp, out + (out_size - 1));
}

// Round 2
// 2172.233 us; speedup vs baseline: 1.3595x; 1.0409x over previous
//
#include <hip/hip_runtime.h>
#include <hip/hip_bf16.h>
#include <stdint.h>

#define T_TOK 4096
#define DIN   4096
#define DOUT  4096
#define NE    8

typedef __attribute__((ext_vector_type(8))) short short8;
typedef __attribute__((ext_vector_type(4))) float floatx4;

__device__ inline uint32_t pk_bf16(float a, float b) {
    __hip_bfloat162 h = __float22bfloat162_rn(make_float2(a, b));
    union { __hip_bfloat162 h; uint32_t u; } cv;
    cv.h = h;
    return cv.u;
}

// async global->LDS, 16B per lane. HW writes at (wave-uniform lds base) + lane*16.
__device__ inline void gll16(const void* g, void* l) {
    __builtin_amdgcn_global_load_lds(
        (const __attribute__((address_space(1))) uint32_t*)g,
        (__attribute__((address_space(3))) uint32_t*)l, 16, 0, 0);
}

// ---------------- fp32 -> bf16 cast (weights) ----------------
__global__ __launch_bounds__(256) void cast_bf16_kernel(const float* __restrict__ src,
                                                        uint16_t* __restrict__ dst) {
    size_t i = ((size_t)blockIdx.x * 256 + threadIdx.x) * 8;
    float4 a = *reinterpret_cast<const float4*>(src + i);
    float4 b = *reinterpret_cast<const float4*>(src + i + 4);
    uint4 p;
    p.x = pk_bf16(a.x, a.y); p.y = pk_bf16(a.z, a.w);
    p.z = pk_bf16(b.x, b.y); p.w = pk_bf16(b.z, b.w);
    *reinterpret_cast<uint4*>(dst + i) = p;
}

// ---------------- gate: logits + top2 + x->bf16 cast (NO global atomics) ----------------
__global__ __launch_bounds__(256) void gate_kernel(
    const float* __restrict__ x, const float* __restrict__ w1,
    const float* __restrict__ w2, uint16_t* __restrict__ xb,
    int2* __restrict__ te, float2* __restrict__ tp)
{
    int t = blockIdx.x;
    int tid = threadIdx.x;
    int g = tid >> 5;      // expert group 0..7
    int l = tid & 31;
    const float* xr = x + (size_t)t * DIN;
    const float* wr = w1 + (size_t)g * DIN;
    uint16_t* xw = xb + (size_t)t * DIN;
    float sum = 0.f;
    for (int i = l * 4; i < DIN; i += 128) {
        float4 xv = *reinterpret_cast<const float4*>(xr + i);
        float4 wv = *reinterpret_cast<const float4*>(wr + i);
        sum += xv.x * wv.x + xv.y * wv.y + xv.z * wv.z + xv.w * wv.w;
        if (g == 0) {
            uint2 p;
            p.x = pk_bf16(xv.x, xv.y);
            p.y = pk_bf16(xv.z, xv.w);
            *reinterpret_cast<uint2*>(xw + i) = p;
        }
    }
#pragma unroll
    for (int off = 16; off; off >>= 1) sum += __shfl_xor(sum, off, 64);

    __shared__ float sh[NE];
    __shared__ float lg[NE];
    if (l == 0) sh[g] = tanhf(sum);
    __syncthreads();
    if (tid < NE) {
        float acc = 0.f;
#pragma unroll
        for (int e2 = 0; e2 < NE; ++e2) acc += sh[e2] * w2[tid * NE + e2];
        lg[tid] = acc;
    }
    __syncthreads();
    if (tid == 0) {
        int i1 = 0; float l1 = lg[0];
        for (int e2 = 1; e2 < NE; ++e2)
            if (lg[e2] > l1) { l1 = lg[e2]; i1 = e2; }
        int i2 = -1; float l2 = -1e30f;
        for (int e2 = 0; e2 < NE; ++e2)
            if (e2 != i1 && lg[e2] > l2) { l2 = lg[e2]; i2 = e2; }
        float ee = expf(l2 - l1);
        te[t] = make_int2(i1, i2);
        tp[t] = make_float2(1.f / (1.f + ee), ee / (1.f + ee));
    }
}

// ---------------- routing: counts, perm/pscore, balance loss (1 block, LDS atomics) ----------------
__global__ __launch_bounds__(256) void route_kernel(
    const int2* __restrict__ te, const float2* __restrict__ tp,
    int* __restrict__ perm, float* __restrict__ pscore,
    int* __restrict__ counts, float* __restrict__ loss_out)
{
    __shared__ int   h[NE];
    __shared__ float impS[NE];
    __shared__ int   curc[NE];
    int tid = threadIdx.x;
    if (tid < NE) { h[tid] = 0; impS[tid] = 0.f; curc[tid] = 0; }
    __syncthreads();
    for (int t = tid; t < T_TOK; t += 256) {
        int2 e = te[t]; float2 p = tp[t];
        atomicAdd(&h[e.x], 1);
        atomicAdd(&h[e.y], 1);
        atomicAdd(&impS[e.x], p.x);
        atomicAdd(&impS[e.y], p.y);
    }
    __syncthreads();
    for (int t = tid; t < T_TOK; t += 256) {
        int2 e = te[t]; float2 p = tp[t];
        int p1 = atomicAdd(&curc[e.x], 1);
        perm[e.x * T_TOK + p1] = t;
        pscore[e.x * T_TOK + p1] = p.x;
        int p2 = atomicAdd(&curc[e.y], 1);
        perm[e.y * T_TOK + p2] = t;
        pscore[e.y * T_TOK + p2] = p.y;
    }
    __syncthreads();
    if (tid == 0) {
        float mi = 0.f, ml = 0.f;
        for (int e = 0; e < NE; ++e) { mi += impS[e]; ml += (float)h[e]; counts[e] = h[e]; }
        mi /= NE; ml /= NE;
        float vi = 0.f, vl = 0.f;
        for (int e = 0; e < NE; ++e) {
            float di = impS[e] - mi; vi += di * di;
            float dl = (float)h[e] - ml; vl += dl * dl;
        }
        vi /= (NE - 1); vl /= (NE - 1);
        *loss_out = 0.01f * (vi / (mi * mi + 1e-10f) + vl / (ml * ml + 1e-10f));
    }
}

// ---------------- expert GEMM: 128x128 tile, BK=32, 2-phase double-buffered ----------------
template<bool PRE>
__global__ __launch_bounds__(256) void moe_gemm_kernel(
    const uint16_t* __restrict__ xb, const uint16_t* __restrict__ wb,
    const float* __restrict__ ew, const float* __restrict__ eb,
    const int* __restrict__ perm, const float* __restrict__ pscore,
    const int* __restrict__ counts, float* __restrict__ out)
{
    const int e = blockIdx.z;
    const int ne = counts[e];
    const int m0 = blockIdx.x * 128;   // m fastest-varying: weight-strip sharers dispatch together
    if (m0 >= ne) return;
    const int n0 = blockIdx.y * 128;
    const int tid  = threadIdx.x;
    const int lane = tid & 63;
    const int wid  = tid >> 6;

    __shared__ int   s_tok[128];
    __shared__ float s_sc[128];
    __shared__ __align__(16) uint16_t As[2][128 * 32];  // linear: row*32 + k
    __shared__ __align__(16) uint16_t Bs[2][128 * 32];

    if (tid < 128) {
        int idx = m0 + tid;
        if (idx < ne) {
            s_tok[tid] = perm[e * T_TOK + idx];
            s_sc[tid]  = pscore[e * T_TOK + idx];
        } else {
            s_tok[tid] = -1;
            s_sc[tid]  = 0.f;
        }
    }
    __syncthreads();

    // staging geometry: each wave covers 16 rows per gll16 issue; lane -> (row, k-quad)
    const int srow = wid * 16 + (lane >> 2);   // 0..63
    const int sq   = (lane & 3) * 8;           // k element offset 0/8/16/24
    int t0 = s_tok[srow];      if (t0 < 0) t0 = 0;
    int t1 = s_tok[64 + srow]; if (t1 < 0) t1 = 0;
    const uint16_t* aS0 = xb + (size_t)t0 * DIN + sq;
    const uint16_t* aS1 = xb + (size_t)t1 * DIN + sq;

    const uint16_t* bS0 = nullptr;
    const uint16_t* bS1 = nullptr;
    const float* fB = nullptr;
    int fRow = 0, fCol = 0;
    if constexpr (PRE) {
        bS0 = wb + (size_t)e * DOUT * DIN + (size_t)(n0 + srow) * DIN + sq;
        bS1 = bS0 + (size_t)64 * DIN;
    } else {
        fRow = tid >> 1; fCol = (tid & 1) * 16;
        fB = ew + (size_t)e * DOUT * DIN + (size_t)(n0 + fRow) * DIN + fCol;
    }

    const int wm   = (wid >> 1) * 64;
    const int wn   = (wid & 1) * 64;
    const int quad = lane >> 4;
    const int mr   = lane & 15;

    floatx4 acc[4][4] = {};

    auto stage = [&](int buf, int kk) {
        gll16(aS0 + kk, &As[buf][wid * 512]);
        gll16(aS1 + kk, &As[buf][2048 + wid * 512]);
        if constexpr (PRE) {
            gll16(bS0 + kk, &Bs[buf][wid * 512]);
            gll16(bS1 + kk, &Bs[buf][2048 + wid * 512]);
        } else {
            float4 f0 = *reinterpret_cast<const float4*>(fB + kk);
            float4 f1 = *reinterpret_cast<const float4*>(fB + kk + 4);
            float4 f2 = *reinterpret_cast<const float4*>(fB + kk + 8);
            float4 f3 = *reinterpret_cast<const float4*>(fB + kk + 12);
            uint4 b0, b1;
            b0.x = pk_bf16(f0.x, f0.y); b0.y = pk_bf16(f0.z, f0.w);
            b0.z = pk_bf16(f1.x, f1.y); b0.w = pk_bf16(f1.z, f1.w);
            b1.x = pk_bf16(f2.x, f2.y); b1.y = pk_bf16(f2.z, f2.w);
            b1.z = pk_bf16(f3.x, f3.y); b1.w = pk_bf16(f3.z, f3.w);
            uint16_t* fD = &Bs[buf][fRow * 32 + fCol];
            *reinterpret_cast<uint4*>(fD)     = b0;
            *reinterpret_cast<uint4*>(fD + 8) = b1;
        }
    };

    auto compute = [&](int buf) {
        short8 af[4], bf4[4];
#pragma unroll
        for (int i = 0; i < 4; ++i)
            af[i] = *reinterpret_cast<const short8*>(&As[buf][(wm + i * 16 + mr) * 32 + quad * 8]);
#pragma unroll
        for (int j = 0; j < 4; ++j)
            bf4[j] = *reinterpret_cast<const short8*>(&Bs[buf][(wn + j * 16 + mr) * 32 + quad * 8]);
#pragma unroll
        for (int i = 0; i < 4; ++i)
#pragma unroll
            for (int j = 0; j < 4; ++j)
                acc[i][j] = __builtin_amdgcn_mfma_f32_16x16x32_bf16(af[i], bf4[j], acc[i][j], 0, 0, 0);
    };

    // 2-phase pipeline: stage(next) issued before compute(cur); one barrier per K-step.
    stage(0, 0);
    __syncthreads();                       // drains vmcnt for buf0
    for (int kk = 0; kk < DIN; kk += 64) {
        stage(1, kk + 32);                 // kk+32 <= 4064 < DIN always
        compute(0);
        __syncthreads();                   // drains buf1 loads; all reads of buf0 done
        if (kk + 64 < DIN) stage(0, kk + 64);
        compute(1);
        __syncthreads();
    }

    // epilogue: out[tok, col] += score * (acc + bias)
    const float* brow = eb + (size_t)e * DOUT + n0 + wn;
    float bj[4];
#pragma unroll
    for (int j = 0; j < 4; ++j) bj[j] = brow[j * 16 + mr];
#pragma unroll
    for (int i = 0; i < 4; ++i) {
#pragma unroll
        for (int r = 0; r < 4; ++r) {
            int idx = wm + i * 16 + quad * 4 + r;
            int tok = s_tok[idx];
            if (tok < 0) continue;
            float sc = s_sc[idx];
            float* orow = out + (size_t)tok * DOUT + n0 + wn;
#pragma unroll
            for (int j = 0; j < 4; ++j)
                atomicAdd(&orow[j * 16 + mr], sc * (acc[i][j][r] + bj[j]));
        }
    }
}

extern "C" void kernel_launch(void* const* d_in, const int* in_sizes, int n_in,
                              void* d_out, int out_size, void* d_ws, size_t ws_size,
                              hipStream_t stream)
{
    const float* x  = (const float*)d_in[0];
    const float* w1 = (const float*)d_in[1];
    const float* w2 = (const float*)d_in[2];
    const float* ew = (const float*)d_in[3];
    const float* eb = (const float*)d_in[4];
    float* out = (float*)d_out;

    // ---- ws layout ----
    // [0, 128K)        perm   (int,   NE*T)
    // [128K, 256K)     pscore (float, NE*T)
    // [256K, 288K)     te     (int2,  T)
    // [288K, 320K)     tp     (float2,T)
    // [320K, +64)      counts
    // [512K, +32M)     xb (bf16 x)
    // [512K+32M, +256M) wb (bf16 weights, if ws allows)
    char* ws = (char*)d_ws;
    int*    perm   = (int*)ws;
    float*  pscore = (float*)(ws + (size_t)128 * 1024);
    int2*   te     = (int2*)(ws + (size_t)256 * 1024);
    float2* tp     = (float2*)(ws + (size_t)288 * 1024);
    int*    counts = (int*)(ws + (size_t)320 * 1024);
    uint16_t* xb   = (uint16_t*)(ws + (size_t)512 * 1024);
    uint16_t* wb   = (uint16_t*)(ws + (size_t)512 * 1024 + (size_t)T_TOK * DIN * 2);

    const size_t need_pre = (size_t)512 * 1024 + (size_t)T_TOK * DIN * 2
                          + (size_t)NE * DOUT * DIN * 2;
    const bool pre = ws_size >= need_pre;

    hipMemsetAsync(d_out, 0, (size_t)out_size * sizeof(float), stream);

    gate_kernel<<<T_TOK, 256, 0, stream>>>(x, w1, w2, xb, te, tp);
    route_kernel<<<1, 256, 0, stream>>>(te, tp, perm, pscore, counts, out + (out_size - 1));
    if (pre) {
        cast_bf16_kernel<<<(int)(((size_t)NE * DOUT * DIN) / 2048), 256, 0, stream>>>(ew, wb);
        moe_gemm_kernel<true><<<dim3(32, 32, 8), 256, 0, stream>>>(
            xb, wb, ew, eb, perm, pscore, counts, out);
    } else {
        moe_gemm_kernel<false><<<dim3(32, 32, 8), 256, 0, stream>>>(
            xb, nullptr, ew, eb, perm, pscore, counts, out);
    }
}

// Round 3
// 1317.858 us; speedup vs baseline: 2.2408x; 1.6483x over previous
//
#include <hip/hip_runtime.h>
#include <hip/hip_bf16.h>
#include <stdint.h>

#define T_TOK 4096
#define DIN   4096
#define DOUT  4096
#define NE    8

typedef __attribute__((ext_vector_type(8))) short short8;
typedef __attribute__((ext_vector_type(4))) float floatx4;

__device__ inline uint32_t pk_bf16(float a, float b) {
    __hip_bfloat162 h = __float22bfloat162_rn(make_float2(a, b));
    union { __hip_bfloat162 h; uint32_t u; } cv;
    cv.h = h;
    return cv.u;
}

// async global->LDS, 16B per lane. HW writes at (wave-uniform lds base) + lane*16.
__device__ inline void gll16(const void* g, void* l) {
    __builtin_amdgcn_global_load_lds(
        (const __attribute__((address_space(1))) uint32_t*)g,
        (__attribute__((address_space(3))) uint32_t*)l, 16, 0, 0);
}

// ---------------- fp32 -> bf16 cast (weights) ----------------
__global__ __launch_bounds__(256) void cast_bf16_kernel(const float* __restrict__ src,
                                                        uint16_t* __restrict__ dst) {
    size_t i = ((size_t)blockIdx.x * 256 + threadIdx.x) * 8;
    float4 a = *reinterpret_cast<const float4*>(src + i);
    float4 b = *reinterpret_cast<const float4*>(src + i + 4);
    uint4 p;
    p.x = pk_bf16(a.x, a.y); p.y = pk_bf16(a.z, a.w);
    p.z = pk_bf16(b.x, b.y); p.w = pk_bf16(b.z, b.w);
    *reinterpret_cast<uint4*>(dst + i) = p;
}

// ---------------- gate: logits + top2 + x->bf16 cast (no global atomics) ----------------
__global__ __launch_bounds__(256) void gate_kernel(
    const float* __restrict__ x, const float* __restrict__ w1,
    const float* __restrict__ w2, uint16_t* __restrict__ xb,
    int2* __restrict__ te, float2* __restrict__ tp)
{
    int t = blockIdx.x;
    int tid = threadIdx.x;
    int g = tid >> 5;      // expert group 0..7
    int l = tid & 31;
    const float* xr = x + (size_t)t * DIN;
    const float* wr = w1 + (size_t)g * DIN;
    uint16_t* xw = xb + (size_t)t * DIN;
    float sum = 0.f;
    for (int i = l * 4; i < DIN; i += 128) {
        float4 xv = *reinterpret_cast<const float4*>(xr + i);
        float4 wv = *reinterpret_cast<const float4*>(wr + i);
        sum += xv.x * wv.x + xv.y * wv.y + xv.z * wv.z + xv.w * wv.w;
        if (g == 0) {
            uint2 p;
            p.x = pk_bf16(xv.x, xv.y);
            p.y = pk_bf16(xv.z, xv.w);
            *reinterpret_cast<uint2*>(xw + i) = p;
        }
    }
#pragma unroll
    for (int off = 16; off; off >>= 1) sum += __shfl_xor(sum, off, 64);

    __shared__ float sh[NE];
    __shared__ float lg[NE];
    if (l == 0) sh[g] = tanhf(sum);
    __syncthreads();
    if (tid < NE) {
        float acc = 0.f;
#pragma unroll
        for (int e2 = 0; e2 < NE; ++e2) acc += sh[e2] * w2[tid * NE + e2];
        lg[tid] = acc;
    }
    __syncthreads();
    if (tid == 0) {
        int i1 = 0; float l1 = lg[0];
        for (int e2 = 1; e2 < NE; ++e2)
            if (lg[e2] > l1) { l1 = lg[e2]; i1 = e2; }
        int i2 = -1; float l2 = -1e30f;
        for (int e2 = 0; e2 < NE; ++e2)
            if (e2 != i1 && lg[e2] > l2) { l2 = lg[e2]; i2 = e2; }
        float ee = expf(l2 - l1);
        te[t] = make_int2(i1, i2);
        tp[t] = make_float2(1.f / (1.f + ee), ee / (1.f + ee));
    }
}

// ---------------- routing: counts, perm/pscore, balance loss (1 block) ----------------
__global__ __launch_bounds__(256) void route_kernel(
    const int2* __restrict__ te, const float2* __restrict__ tp,
    int* __restrict__ perm, float* __restrict__ pscore,
    int* __restrict__ counts, float* __restrict__ loss_out)
{
    __shared__ int   h[NE];
    __shared__ float impS[NE];
    __shared__ int   curc[NE];
    int tid = threadIdx.x;
    if (tid < NE) { h[tid] = 0; impS[tid] = 0.f; curc[tid] = 0; }
    __syncthreads();
    for (int t = tid; t < T_TOK; t += 256) {
        int2 e = te[t]; float2 p = tp[t];
        atomicAdd(&h[e.x], 1);
        atomicAdd(&h[e.y], 1);
        atomicAdd(&impS[e.x], p.x);
        atomicAdd(&impS[e.y], p.y);
    }
    __syncthreads();
    for (int t = tid; t < T_TOK; t += 256) {
        int2 e = te[t]; float2 p = tp[t];
        int p1 = atomicAdd(&curc[e.x], 1);
        perm[e.x * T_TOK + p1] = t;
        pscore[e.x * T_TOK + p1] = p.x;
        int p2 = atomicAdd(&curc[e.y], 1);
        perm[e.y * T_TOK + p2] = t;
        pscore[e.y * T_TOK + p2] = p.y;
    }
    __syncthreads();
    if (tid == 0) {
        float mi = 0.f, ml = 0.f;
        for (int e = 0; e < NE; ++e) { mi += impS[e]; ml += (float)h[e]; counts[e] = h[e]; }
        mi /= NE; ml /= NE;
        float vi = 0.f, vl = 0.f;
        for (int e = 0; e < NE; ++e) {
            float di = impS[e] - mi; vi += di * di;
            float dl = (float)h[e] - ml; vl += dl * dl;
        }
        vi /= (NE - 1); vl /= (NE - 1);
        *loss_out = 0.01f * (vi / (mi * mi + 1e-10f) + vl / (ml * ml + 1e-10f));
    }
}

// ---------------- expert GEMM: 128x128 tile, BK=32, 4-buffer depth-2 pipeline ----------------
// Counted vmcnt (T4): 2 stages (8 global_load_lds) stay in flight across the barrier.
// Hazard ledger: buffer reused after 4 tiles; stage(t+2) overwrites buf read by
// compute(t-2), separated by barriers of iters t-1 and t -> single barrier/iter safe.
// XCD swizzle: all 32 m-blocks of one (y,e) B-strip share b&7 (same XCD L2), clustered in time.
template<bool PRE>
__global__ __launch_bounds__(256) void moe_gemm_kernel(
    const uint16_t* __restrict__ xb, const uint16_t* __restrict__ wb,
    const float* __restrict__ ew, const float* __restrict__ eb,
    const int* __restrict__ perm, const float* __restrict__ pscore,
    const int* __restrict__ counts, float* __restrict__ out)
{
    const int b = blockIdx.x;                  // 0..8191
    const int G = (b & 7) + ((b >> 8) << 3);   // strip id 0..255, XCD = b&7
    const int x = (b >> 3) & 31;               // m-block within strip
    const int y = G & 31;
    const int e = G >> 5;
    const int ne = counts[e];
    const int m0 = x * 128;
    if (m0 >= ne) return;                      // uniform exit, no barrier divergence
    const int n0 = y * 128;
    const int tid  = threadIdx.x;
    const int lane = tid & 63;
    const int wid  = tid >> 6;

    __shared__ __align__(16) uint16_t As[4][128 * 32];  // 4 x 8KB
    __shared__ __align__(16) uint16_t Bs[4][128 * 32];  // 4 x 8KB  (total exactly 64 KiB)

    // staging geometry: each wave covers 16 rows per gll16; lane -> (row, k-quad)
    const int srow = wid * 16 + (lane >> 2);   // 0..63
    const int sq   = (lane & 3) * 8;           // k elem offset 0/8/16/24
    const int i0 = m0 + srow, i1 = m0 + 64 + srow;
    const int t0 = (i0 < ne) ? perm[e * T_TOK + i0] : 0;
    const int t1 = (i1 < ne) ? perm[e * T_TOK + i1] : 0;
    const uint16_t* aS0 = xb + (size_t)t0 * DIN + sq;
    const uint16_t* aS1 = xb + (size_t)t1 * DIN + sq;

    const uint16_t* bS0 = nullptr;
    const uint16_t* bS1 = nullptr;
    const float* fB = nullptr;
    int fRow = 0, fCol = 0;
    if constexpr (PRE) {
        bS0 = wb + (size_t)e * DOUT * DIN + (size_t)(n0 + srow) * DIN + sq;
        bS1 = bS0 + (size_t)64 * DIN;
    } else {
        fRow = tid >> 1; fCol = (tid & 1) * 16;
        fB = ew + (size_t)e * DOUT * DIN + (size_t)(n0 + fRow) * DIN + fCol;
    }

    const int wm   = (wid >> 1) * 64;
    const int wn   = (wid & 1) * 64;
    const int quad = lane >> 4;
    const int mr   = lane & 15;

    floatx4 acc[4][4] = {};

    auto stage = [&](int buf, int kk) {
        gll16(aS0 + kk, &As[buf][wid * 512]);
        gll16(aS1 + kk, &As[buf][2048 + wid * 512]);
        if constexpr (PRE) {
            gll16(bS0 + kk, &Bs[buf][wid * 512]);
            gll16(bS1 + kk, &Bs[buf][2048 + wid * 512]);
        } else {
            float4 f0 = *reinterpret_cast<const float4*>(fB + kk);
            float4 f1 = *reinterpret_cast<const float4*>(fB + kk + 4);
            float4 f2 = *reinterpret_cast<const float4*>(fB + kk + 8);
            float4 f3 = *reinterpret_cast<const float4*>(fB + kk + 12);
            uint4 b0, b1;
            b0.x = pk_bf16(f0.x, f0.y); b0.y = pk_bf16(f0.z, f0.w);
            b0.z = pk_bf16(f1.x, f1.y); b0.w = pk_bf16(f1.z, f1.w);
            b1.x = pk_bf16(f2.x, f2.y); b1.y = pk_bf16(f2.z, f2.w);
            b1.z = pk_bf16(f3.x, f3.y); b1.w = pk_bf16(f3.z, f3.w);
            uint16_t* fD = &Bs[buf][fRow * 32 + fCol];
            *reinterpret_cast<uint4*>(fD)     = b0;
            *reinterpret_cast<uint4*>(fD + 8) = b1;
        }
    };

    auto compute = [&](int buf) {
        short8 af[4], bf4[4];
#pragma unroll
        for (int i = 0; i < 4; ++i)
            af[i] = *reinterpret_cast<const short8*>(&As[buf][(wm + i * 16 + mr) * 32 + quad * 8]);
#pragma unroll
        for (int j = 0; j < 4; ++j)
            bf4[j] = *reinterpret_cast<const short8*>(&Bs[buf][(wn + j * 16 + mr) * 32 + quad * 8]);
#pragma unroll
        for (int i = 0; i < 4; ++i)
#pragma unroll
            for (int j = 0; j < 4; ++j)
                acc[i][j] = __builtin_amdgcn_mfma_f32_16x16x32_bf16(af[i], bf4[j], acc[i][j], 0, 0, 0);
    };

    // prologue: two stages in flight
    stage(0, 0);
    stage(1, 32);
    // main loop: one barrier + counted vmcnt per K-step; loads span barriers
    for (int t = 0; t < 126; ++t) {
        stage((t + 2) & 3, (t + 2) * 32);
        if constexpr (PRE) {
            asm volatile("s_waitcnt vmcnt(8)" ::: "memory");  // stage t landed; t+1,t+2 in flight
            __builtin_amdgcn_s_barrier();
            __builtin_amdgcn_sched_barrier(0);
        } else {
            __syncthreads();
        }
        compute(t & 3);
    }
    // tail: drain 4 -> 0
    if constexpr (PRE) {
        asm volatile("s_waitcnt vmcnt(4)" ::: "memory");
        __builtin_amdgcn_s_barrier();
        __builtin_amdgcn_sched_barrier(0);
    } else { __syncthreads(); }
    compute(2);   // t = 126
    if constexpr (PRE) {
        asm volatile("s_waitcnt vmcnt(0)" ::: "memory");
        __builtin_amdgcn_s_barrier();
        __builtin_amdgcn_sched_barrier(0);
    } else { __syncthreads(); }
    compute(3);   // t = 127

    // epilogue: out[tok, col] += score * (acc + bias); tokens read directly from perm
    const float* brow = eb + (size_t)e * DOUT + n0 + wn;
    float bj[4];
#pragma unroll
    for (int j = 0; j < 4; ++j) bj[j] = brow[j * 16 + mr];
#pragma unroll
    for (int i = 0; i < 4; ++i) {
#pragma unroll
        for (int r = 0; r < 4; ++r) {
            int gidx = m0 + wm + i * 16 + quad * 4 + r;
            if (gidx >= ne) continue;
            int tok  = perm[e * T_TOK + gidx];
            float sc = pscore[e * T_TOK + gidx];
            float* orow = out + (size_t)tok * DOUT + n0 + wn;
#pragma unroll
            for (int j = 0; j < 4; ++j)
                atomicAdd(&orow[j * 16 + mr], sc * (acc[i][j][r] + bj[j]));
        }
    }
}

extern "C" void kernel_launch(void* const* d_in, const int* in_sizes, int n_in,
                              void* d_out, int out_size, void* d_ws, size_t ws_size,
                              hipStream_t stream)
{
    const float* x  = (const float*)d_in[0];
    const float* w1 = (const float*)d_in[1];
    const float* w2 = (const float*)d_in[2];
    const float* ew = (const float*)d_in[3];
    const float* eb = (const float*)d_in[4];
    float* out = (float*)d_out;

    // ---- ws layout ----
    // [0, 128K)  perm | [128K, 256K) pscore | [256K, 288K) te | [288K, 320K) tp
    // [320K, +64) counts | [512K, +32M) xb | [512K+32M, +256M) wb
    char* ws = (char*)d_ws;
    int*    perm   = (int*)ws;
    float*  pscore = (float*)(ws + (size_t)128 * 1024);
    int2*   te     = (int2*)(ws + (size_t)256 * 1024);
    float2* tp     = (float2*)(ws + (size_t)288 * 1024);
    int*    counts = (int*)(ws + (size_t)320 * 1024);
    uint16_t* xb   = (uint16_t*)(ws + (size_t)512 * 1024);
    uint16_t* wb   = (uint16_t*)(ws + (size_t)512 * 1024 + (size_t)T_TOK * DIN * 2);

    const size_t need_pre = (size_t)512 * 1024 + (size_t)T_TOK * DIN * 2
                          + (size_t)NE * DOUT * DIN * 2;
    const bool pre = ws_size >= need_pre;

    hipMemsetAsync(d_out, 0, (size_t)out_size * sizeof(float), stream);

    gate_kernel<<<T_TOK, 256, 0, stream>>>(x, w1, w2, xb, te, tp);
    route_kernel<<<1, 256, 0, stream>>>(te, tp, perm, pscore, counts, out + (out_size - 1));
    if (pre) {
        cast_bf16_kernel<<<(int)(((size_t)NE * DOUT * DIN) / 2048), 256, 0, stream>>>(ew, wb);
        moe_gemm_kernel<true><<<8192, 256, 0, stream>>>(
            xb, wb, ew, eb, perm, pscore, counts, out);
    } else {
        moe_gemm_kernel<false><<<8192, 256, 0, stream>>>(
            xb, nullptr, ew, eb, perm, pscore, counts, out);
    }
}